// Round 2
// baseline (73258.417 us; speedup 1.0000x reference)
//
#include <hip/hip_runtime.h>

typedef unsigned short u16;
typedef unsigned long long u64;
typedef __attribute__((ext_vector_type(8))) short bf16x8;
typedef __attribute__((ext_vector_type(4))) float f32x4;

#define MFMA(a,b,c) __builtin_amdgcn_mfma_f32_16x16x32_bf16(a,b,c,0,0,0)

#define B_   128
#define T_   200
#define F_   171
#define FP_  192          // padded frame (6 K-chunks of 32)
#define H_   1024
#define G_   4096
#define K1_  1216         // FP_ + H_
#define K2_  2048         // H_ + H_
#define TF_  (T_*F_)      // 34200
#define BH_  (B_*H_)
#define NB_  512
#define NT_  256

__device__ __forceinline__ u16 f2bf(float v){
  union { float f; unsigned u; } c; c.f = v;
  unsigned r = (c.u + 0x7fffu + ((c.u >> 16) & 1u)) >> 16;   // RNE
  return (u16)r;
}
__device__ __forceinline__ float bf2f(u16 h){
  union { unsigned u; float f; } c; c.u = ((unsigned)h) << 16; return c.f;
}
__device__ __forceinline__ bf16x8 ld8(const u16* p){
  return *reinterpret_cast<const bf16x8*>(p);
}
// coherent (agent-scope) 16B activation load: bypasses stale L1 / per-XCD L2
__device__ __forceinline__ bf16x8 ld8a(const u16* p){
  union { bf16x8 v; u64 q[2]; } u;
  u.q[0] = __hip_atomic_load((const u64*)p,       __ATOMIC_RELAXED, __HIP_MEMORY_SCOPE_AGENT);
  u.q[1] = __hip_atomic_load((const u64*)(p + 4), __ATOMIC_RELAXED, __HIP_MEMORY_SCOPE_AGENT);
  return u.v;
}
__device__ __forceinline__ void st2a(u16* p, u16 v){
  __hip_atomic_store(p, v, __ATOMIC_RELAXED, __HIP_MEMORY_SCOPE_AGENT);
}
__device__ __forceinline__ float sigm(float v){ return 1.f / (1.f + __expf(-v)); }

// ---------------- device-wide barrier: release-only, NO cache invalidate ----------------
__device__ __forceinline__ void gbar(unsigned* cnt, unsigned ep, int tid){
  __syncthreads();
  if (tid == 0){
    __builtin_amdgcn_fence(__ATOMIC_RELEASE, "agent");   // wbl2: flush our stores, no inval
    atomicAdd(cnt, 1u);
    const unsigned tgt = ep * (unsigned)NB_;
    while (__hip_atomic_load(cnt, __ATOMIC_RELAXED, __HIP_MEMORY_SCOPE_AGENT) < tgt)
      __builtin_amdgcn_s_sleep(1);
    // no acquire fence: all cross-block reads use agent-scope (sc) loads
  }
  __syncthreads();
}

// ---------------- K-segment GEMM: KC chunks of 32, 4 independent acc chains ----------------
template<int KC>
__device__ __forceinline__ void gemm_seg(const u16* __restrict__ wp,
                                         const u16* ah, const u16* al,
                                         f32x4 (&acc)[4])
{
#pragma unroll
  for (int kc = 0; kc < KC; ++kc){
    bf16x8 bw = ld8(wp + kc*32);          // weight: plain cached load
    bf16x8 ph = ld8a(ah + kc*32);         // activations: coherent loads
    bf16x8 pl = ld8a(al + kc*32);
    acc[(kc & 1)]     = MFMA(ph, bw, acc[(kc & 1)]);
    acc[2 + (kc & 1)] = MFMA(pl, bw, acc[2 + (kc & 1)]);
  }
}

// ---------------- gate tile -> cell update (16 batches x 16 units per block) ----------------
__device__ __forceinline__ void finish_store(
    f32x4 (&acc)[4], const float* __restrict__ bias_l, float* __restrict__ c_l,
    u16* __restrict__ ohh, u16* __restrict__ ohl,
    int wn, int ke, int r16, int tid, int cidx, float (*lds)[16][17])
{
  f32x4 a;
#pragma unroll
  for (int r = 0; r < 4; ++r) a[r] = (acc[0][r] + acc[1][r]) + (acc[2][r] + acc[3][r]);
  const float bs = bias_l[r16];            // D: col = lane&15, row = (lane>>4)*4 + r
#pragma unroll
  for (int r = 0; r < 4; ++r) lds[wn][ke*4 + r][r16] = a[r] + bs;
  __syncthreads();
  {
    const int bl = tid >> 4, ul = tid & 15;
    const float gi = lds[0][bl][ul], gf = lds[1][bl][ul];
    const float gg = lds[2][bl][ul], go = lds[3][bl][ul];
    const float co = c_l[cidx];
    const float cn = sigm(gf)*co + sigm(gi)*tanhf(gg);
    const float hn = sigm(go)*tanhf(cn);
    c_l[cidx] = cn;                        // c is block-private: plain access
    const u16 hh = f2bf(hn);
    st2a(ohh + cidx, hh);                  // h crosses blocks: coherent stores
    st2a(ohl + cidx, f2bf(hn - bf2f(hh)));
  }
}

// ---------------- main persistent kernel: 512 blocks (2/CU), 8 mg x 64 ng ----------------
__global__ __launch_bounds__(NT_, 2) void k_main(
    const float* __restrict__ x, float* __restrict__ out,
    const u16* __restrict__ W1, const u16* __restrict__ W2,
    const u16* __restrict__ W3, const u16* __restrict__ WD,
    const float* __restrict__ bperm, const float* __restrict__ bdec,
    u16* __restrict__ h_hi, u16* __restrict__ h_lo, float* __restrict__ cst,
    u16* __restrict__ if_hi, u16* __restrict__ if_lo,
    unsigned* __restrict__ bar)
{
  const int tid = threadIdx.x, bid = blockIdx.x;
  const int mg = bid >> 6, ng = bid & 63;           // 8 batch-groups x 64 unit-groups
  const int wn = tid >> 6, lane = tid & 63;         // wave = gate type (i,f,g,o)
  const int r16 = lane & 15, ke = lane >> 4;
  __shared__ float lds[4][16][17];
  unsigned ep = 0;

  const int wrow = ng*64 + wn*16 + r16;
  const u16* w1x = W1 + (size_t)wrow*K1_ + ke*8;    // kc 0..5  (in_frame part)
  const u16* w1h = w1x + FP_;                        // kc 0..31 (h0 part)
  const u16* w2x = W2 + (size_t)wrow*K2_ + ke*8;
  const u16* w2h = w2x + H_;
  const u16* w3x = W3 + (size_t)wrow*K2_ + ke*8;
  const u16* w3h = w3x + H_;

  const int b0   = mg*16 + r16;                     // A-frag batch row
  const int aH   = b0*H_  + ke*8;
  const int aF   = b0*FP_ + ke*8;
  const int cidx = (mg*16 + (tid >> 4))*H_ + ng*16 + (tid & 15);

  f32x4 acc[4];
#pragma unroll
  for (int i = 0; i < 4; ++i) acc[i] = (f32x4){0,0,0,0};   // L1-h partial for t=0 (h0=0)

  for (int t = 0; t < T_; ++t){
    const int cur = t & 1, prv = cur ^ 1;

    // ---------- P1: L1 x-part (6 kc) on top of carried h-part partial + cell ----------
    gemm_seg<6>(w1x, if_hi + aF, if_lo + aF, acc);
    finish_store(acc, bperm + 0*G_ + ng*64 + wn*16, cst + 0*BH_,
                 h_hi + (0*2+cur)*BH_, h_lo + (0*2+cur)*BH_,
                 wn, ke, r16, tid, cidx, lds);
    ++ep; gbar(bar, ep, tid);

    // ---------- P2: L2 = [h0_cur | h1_prev] ----------
#pragma unroll
    for (int i = 0; i < 4; ++i) acc[i] = (f32x4){0,0,0,0};
    gemm_seg<32>(w2x, h_hi + (0*2+cur)*BH_ + aH, h_lo + (0*2+cur)*BH_ + aH, acc);
    gemm_seg<32>(w2h, h_hi + (1*2+prv)*BH_ + aH, h_lo + (1*2+prv)*BH_ + aH, acc);
    finish_store(acc, bperm + 1*G_ + ng*64 + wn*16, cst + 1*BH_,
                 h_hi + (1*2+cur)*BH_, h_lo + (1*2+cur)*BH_,
                 wn, ke, r16, tid, cidx, lds);
    ++ep; gbar(bar, ep, tid);

    // ---------- P3: L3 = [h1_cur | h2_prev] ----------
#pragma unroll
    for (int i = 0; i < 4; ++i) acc[i] = (f32x4){0,0,0,0};
    gemm_seg<32>(w3x, h_hi + (1*2+cur)*BH_ + aH, h_lo + (1*2+cur)*BH_ + aH, acc);
    gemm_seg<32>(w3h, h_hi + (2*2+prv)*BH_ + aH, h_lo + (2*2+prv)*BH_ + aH, acc);
    finish_store(acc, bperm + 2*G_ + ng*64 + wn*16, cst + 2*BH_,
                 h_hi + (2*2+cur)*BH_, h_lo + (2*2+cur)*BH_,
                 wn, ke, r16, tid, cidx, lds);
    ++ep; gbar(bar, ep, tid);

    // ---------- P4: decoder (88 blocks) + precompute L1 h-part for t+1 (all blocks) ----------
    if (bid < 88){                                   // 8 batch-tiles x 11 col-tiles
      const int mb = bid / 11, nt = bid - mb*11;
      const u16* h2h = h_hi + (2*2+cur)*BH_;
      const u16* h2l = h_lo + (2*2+cur)*BH_;
      const u16* wp  = WD + (size_t)(nt*16 + r16)*H_ + ke*8;
      const int doff = (mb*16 + r16)*H_ + ke*8;
      f32x4 d0 = {0,0,0,0}, d1 = {0,0,0,0};
#pragma unroll
      for (int j = 0; j < 8; ++j){                   // 4 waves split K=1024
        const int kc = wn*8 + j;
        bf16x8 bw = ld8(wp + kc*32);
        bf16x8 ph = ld8a(h2h + doff + kc*32);
        bf16x8 pl = ld8a(h2l + doff + kc*32);
        d0 = MFMA(ph, bw, d0);
        d1 = MFMA(pl, bw, d1);
      }
#pragma unroll
      for (int r = 0; r < 4; ++r) lds[wn][ke*4 + r][r16] = d0[r] + d1[r];
      __syncthreads();
      {
        const int bl = tid >> 4, fl = tid & 15;      // 256 threads = 16x16 tile
        float v = lds[0][bl][fl] + lds[1][bl][fl]
                + lds[2][bl][fl] + lds[3][bl][fl] + bdec[nt*16 + fl];
        const int f = nt*16 + fl, b = mb*16 + bl;
        if (f < F_) out[(size_t)b*TF_ + (size_t)t*F_ + f] = v;
        if (t + 1 < T_){
          float in = 0.f;
          if (f < F_){
            const bool gt = (((t+1) % 10) < 5);
            in = gt ? x[(size_t)b*TF_ + (size_t)(t+1)*F_ + f] : v;
          }
          const u16 hh = f2bf(in);
          st2a(if_hi + b*FP_ + f, hh);
          st2a(if_lo + b*FP_ + f, f2bf(in - bf2f(hh)));
        }
      }
    }
#pragma unroll
    for (int i = 0; i < 4; ++i) acc[i] = (f32x4){0,0,0,0};
    gemm_seg<32>(w1h, h_hi + (0*2+cur)*BH_ + aH, h_lo + (0*2+cur)*BH_ + aH, acc);
    ++ep; gbar(bar, ep, tid);                        // acc carries into P1 of t+1
  }
}

// ---------------- prep: permuted biases, decoder bias, initial in_frame ----------------
__global__ void k_prep(const float* __restrict__ x,
                       const float* bi1, const float* bh1,
                       const float* bi2, const float* bh2,
                       const float* bi3, const float* bh3,
                       const float* bd_in,
                       float* __restrict__ bperm, float* __restrict__ bdec,
                       u16* __restrict__ if_hi, u16* __restrict__ if_lo)
{
  const int i = blockIdx.x * blockDim.x + threadIdx.x;
  if (i < 3*G_){
    const int l = i >> 12, r = i & 4095;
    const int ng = r >> 6, g = (r >> 4) & 3, u = r & 15;
    const int j = (g << 10) | (ng << 4) | u;          // original gate row
    const float* bi = (l == 0) ? bi1 : (l == 1) ? bi2 : bi3;
    const float* bh = (l == 0) ? bh1 : (l == 1) ? bh2 : bh3;
    bperm[i] = bi[j] + bh[j];
  }
  const int i2 = i - 3*G_;
  if (i2 >= 0 && i2 < FP_) bdec[i2] = (i2 < F_) ? bd_in[i2] : 0.f;
  const int i3 = i2 - FP_;
  if (i3 >= 0 && i3 < B_*FP_){
    const int b = i3 / FP_, f = i3 - b*FP_;
    const float v = (f < F_) ? x[(size_t)b*TF_ + f] : 0.f;   // t=0 is ground-truth
    const u16 hh = f2bf(v);
    if_hi[i3] = hh;
    if_lo[i3] = f2bf(v - bf2f(hh));
  }
}

// ---------------- weight convert: fp32 -> bf16, gate-permuted & concatenated ----------------
__global__ void k_wcvt(const float* __restrict__ Wih1, const float* __restrict__ Whh1,
                       const float* __restrict__ Wih2, const float* __restrict__ Whh2,
                       const float* __restrict__ Wih3, const float* __restrict__ Whh3,
                       const float* __restrict__ Wd_in,
                       u16* __restrict__ W1, u16* __restrict__ W2,
                       u16* __restrict__ W3, u16* __restrict__ WD)
{
  const int region = blockIdx.y;
  const size_t stride = (size_t)gridDim.x * blockDim.x;
  const size_t i0 = (size_t)blockIdx.x * blockDim.x + threadIdx.x;
  if (region == 0){
    for (size_t i = i0; i < (size_t)G_*K1_; i += stride){
      const int r = (int)(i / K1_), k = (int)(i - (size_t)r*K1_);
      const int ng = r >> 6, g = (r >> 4) & 3, u = r & 15;
      const int j = (g << 10) | (ng << 4) | u;
      float v;
      if (k < FP_) v = (k < F_) ? Wih1[(size_t)j*F_ + k] : 0.f;
      else         v = Whh1[(size_t)j*H_ + (k - FP_)];
      W1[i] = f2bf(v);
    }
  } else if (region == 1){
    for (size_t i = i0; i < (size_t)G_*K2_; i += stride){
      const int r = (int)(i / K2_), k = (int)(i - (size_t)r*K2_);
      const int ng = r >> 6, g = (r >> 4) & 3, u = r & 15;
      const int j = (g << 10) | (ng << 4) | u;
      const float v = (k < H_) ? Wih2[(size_t)j*H_ + k] : Whh2[(size_t)j*H_ + (k - H_)];
      W2[i] = f2bf(v);
    }
  } else if (region == 2){
    for (size_t i = i0; i < (size_t)G_*K2_; i += stride){
      const int r = (int)(i / K2_), k = (int)(i - (size_t)r*K2_);
      const int ng = r >> 6, g = (r >> 4) & 3, u = r & 15;
      const int j = (g << 10) | (ng << 4) | u;
      const float v = (k < H_) ? Wih3[(size_t)j*H_ + k] : Whh3[(size_t)j*H_ + (k - H_)];
      W3[i] = f2bf(v);
    }
  } else {
    for (size_t i = i0; i < (size_t)176*H_; i += stride){
      const int r = (int)(i >> 10), k = (int)(i & (H_ - 1));
      WD[i] = f2bf((r < F_) ? Wd_in[(size_t)r*H_ + k] : 0.f);
    }
  }
}

extern "C" void kernel_launch(void* const* d_in, const int* in_sizes, int n_in,
                              void* d_out, int out_size, void* d_ws, size_t ws_size,
                              hipStream_t stream)
{
  const float* x    = (const float*)d_in[0];
  const float* Wih1 = (const float*)d_in[1];
  const float* bih1 = (const float*)d_in[2];
  const float* Whh1 = (const float*)d_in[3];
  const float* bhh1 = (const float*)d_in[4];
  const float* Wih2 = (const float*)d_in[5];
  const float* bih2 = (const float*)d_in[6];
  const float* Whh2 = (const float*)d_in[7];
  const float* bhh2 = (const float*)d_in[8];
  const float* Wih3 = (const float*)d_in[9];
  const float* bih3 = (const float*)d_in[10];
  const float* Whh3 = (const float*)d_in[11];
  const float* bhh3 = (const float*)d_in[12];
  const float* Wdec = (const float*)d_in[13];
  const float* bdec_in = (const float*)d_in[14];
  float* out = (float*)d_out;

  char* ws = (char*)d_ws;
  size_t off = 0;
  auto alloc = [&](size_t bytes) -> void* {
    void* p = ws + off;
    off = (off + bytes + 255) & ~(size_t)255;
    return p;
  };
  unsigned* bar = (unsigned*)alloc(256);
  u16* h_hi  = (u16*)alloc((size_t)3*2*BH_*2);
  u16* h_lo  = (u16*)alloc((size_t)3*2*BH_*2);
  float* cst = (float*)alloc((size_t)3*BH_*4);
  u16* if_hi = (u16*)alloc((size_t)B_*FP_*2);
  u16* if_lo = (u16*)alloc((size_t)B_*FP_*2);
  const size_t zero_bytes = off;                 // state zone: re-zeroed every launch
  u16* W1 = (u16*)alloc((size_t)G_*K1_*2);
  u16* W2 = (u16*)alloc((size_t)G_*K2_*2);
  u16* W3 = (u16*)alloc((size_t)G_*K2_*2);
  u16* WD = (u16*)alloc((size_t)176*H_*2);
  float* bperm = (float*)alloc((size_t)3*G_*4);
  float* bdec  = (float*)alloc((size_t)FP_*4);

  hipMemsetAsync(d_ws, 0, zero_bytes, stream);
  k_prep<<<145, 256, 0, stream>>>(x, bih1, bhh1, bih2, bhh2, bih3, bhh3, bdec_in,
                                  bperm, bdec, if_hi, if_lo);
  k_wcvt<<<dim3(2048, 4), 256, 0, stream>>>(Wih1, Whh1, Wih2, Whh2, Wih3, Whh3, Wdec,
                                            W1, W2, W3, WD);
  k_main<<<NB_, NT_, 0, stream>>>(x, out, W1, W2, W3, WD, bperm, bdec,
                                  h_hi, h_lo, cst, if_hi, if_lo, bar);
}

// Round 3
// 33147.672 us; speedup vs baseline: 2.2101x; 2.2101x over previous
//
#include <hip/hip_runtime.h>

typedef unsigned short u16;
typedef __attribute__((ext_vector_type(8))) short bf16x8;
typedef __attribute__((ext_vector_type(4))) float f32x4;

#define MFMA(a,b,c) __builtin_amdgcn_mfma_f32_16x16x32_bf16(a,b,c,0,0,0)

#define B_   128
#define T_   200
#define F_   171
#define FX_  256          // padded frame (8 K-chunks of 32; zero-padded weights)
#define H_   1024
#define G_   4096
#define TF_  (T_*F_)
#define BH_  (B_*H_)
#define NB_  512
#define NT_  256

__device__ __forceinline__ u16 f2bf(float v){
  union { float f; unsigned u; } c; c.f = v;
  unsigned r = (c.u + 0x7fffu + ((c.u >> 16) & 1u)) >> 16;   // RNE
  return (u16)r;
}
__device__ __forceinline__ float bf2f(u16 h){
  union { unsigned u; float f; } c; c.u = ((unsigned)h) << 16; return c.f;
}
__device__ __forceinline__ bf16x8 ld8(const u16* p){
  return *reinterpret_cast<const bf16x8*>(p);
}
__device__ __forceinline__ float sigm(float v){ return 1.f / (1.f + __expf(-v)); }

// ---------- device-wide barrier: release-wb, hierarchical arrive, acquire-inv ----------
__device__ __forceinline__ void gbar(unsigned* bar, unsigned ep, int tid, int bid){
  __syncthreads();
  if (tid == 0){
    __builtin_amdgcn_fence(__ATOMIC_RELEASE, "agent");       // write-back, no inval
    unsigned* leaf = bar + (bid >> 4) * 16;                  // 32 leaves x 16 blocks
    unsigned* root = bar + 32 * 16;
    const unsigned old = atomicAdd(leaf, 1u);
    if (old == ep * 16u - 1u) atomicAdd(root, 1u);           // leaf closer bumps root
    while (__hip_atomic_load(root, __ATOMIC_RELAXED, __HIP_MEMORY_SCOPE_AGENT) < ep * 32u)
      __builtin_amdgcn_s_sleep(2);
    __builtin_amdgcn_fence(__ATOMIC_ACQUIRE, "agent");       // invalidate stale lines
  }
  __syncthreads();
}

// ---------- K-quarter GEMM: KC chunks of 32, 4 col-tiles, hi/lo chains ----------
template<int KC, int KS>
__device__ __forceinline__ void gemm(const u16* __restrict__ Wb,
                                     const u16* __restrict__ Ah, const u16* __restrict__ Al,
                                     f32x4 (&gh)[4], f32x4 (&gl)[4])
{
#pragma unroll
  for (int kc = 0; kc < KC; ++kc){
    const bf16x8 pa = ld8(Ah + kc*32);
    const bf16x8 pl = ld8(Al + kc*32);
#pragma unroll
    for (int tt = 0; tt < 4; ++tt){
      const bf16x8 bw = ld8(Wb + (size_t)tt*16*KS + kc*32);
      gh[tt] = MFMA(pa, bw, gh[tt]);
      gl[tt] = MFMA(pl, bw, gl[tt]);
    }
  }
}
__device__ __forceinline__ void zacc(f32x4 (&gh)[4], f32x4 (&gl)[4]){
#pragma unroll
  for (int i = 0; i < 4; ++i){ gh[i] = (f32x4){0,0,0,0}; gl[i] = (f32x4){0,0,0,0}; }
}

// ---------- cross-wave K-reduce + cell update (block: 16 batches x 16 units) ----------
__device__ __forceinline__ void reduce_cell(
    f32x4 (&gh)[4], f32x4 (&gl)[4],
    const float* __restrict__ bias64, float* __restrict__ c_l,
    u16* __restrict__ ohh, u16* __restrict__ ohl,
    int mg, int ug, int w, int ke, int r16, int tid, float (*red)[16][69])
{
#pragma unroll
  for (int tt = 0; tt < 4; ++tt){
#pragma unroll
    for (int r = 0; r < 4; ++r)
      red[w][ke*4 + r][tt*16 + r16] = gh[tt][r] + gl[tt][r];  // D: row=ke*4+r, col=lane&15
  }
  __syncthreads();
  {
    const int bl = tid >> 4, u = tid & 15;
    float g[4];
#pragma unroll
    for (int gg = 0; gg < 4; ++gg)
      g[gg] = red[0][bl][gg*16+u] + red[1][bl][gg*16+u]
            + red[2][bl][gg*16+u] + red[3][bl][gg*16+u] + bias64[gg*16 + u];
    const int idx = (mg*16 + bl)*H_ + ug*16 + u;
    const float co = c_l[idx];
    const float cn = sigm(g[1])*co + sigm(g[0])*tanhf(g[2]);
    const float hn = sigm(g[3])*tanhf(cn);
    c_l[idx] = cn;
    const u16 hh = f2bf(hn);
    ohh[idx] = hh;
    ohl[idx] = f2bf(hn - bf2f(hh));
  }
}

// ---------- main persistent kernel: 512 blocks (2/CU), 8 mg x 64 ug ----------
__global__ __launch_bounds__(NT_, 2) void k_main(
    const float* __restrict__ x, float* __restrict__ out,
    const u16* __restrict__ W1X, const u16* __restrict__ W1H,
    const u16* __restrict__ W2,  const u16* __restrict__ W3,
    const u16* __restrict__ WD,
    const float* __restrict__ bperm, const float* __restrict__ bdec,
    u16* __restrict__ h_hi, u16* __restrict__ h_lo, float* __restrict__ cst,
    u16* __restrict__ if_hi, u16* __restrict__ if_lo,
    unsigned* __restrict__ bar)
{
  const int tid = threadIdx.x, bid = blockIdx.x;
  const int mg = bid >> 6, ug = bid & 63;       // bid%8 == ug%8 -> column slice per XCD
  const int w = tid >> 6, lane = tid & 63;      // 4 waves split K
  const int r16 = lane & 15, ke = lane >> 4;
  __shared__ float red[4][16][69];
  unsigned ep = 0;

  const size_t wcol = (size_t)(ug*64 + r16);
  const u16* w1xB = W1X + wcol*FX_  + w*64          + ke*8;   // K=256, quarter 64
  const u16* w1hB = W1H + wcol*1024 + w*256         + ke*8;   // K=1024, quarter 256
  const u16* w2B  = W2  + wcol*2048 + (w>>1)*1024 + (w&1)*512 + ke*8;
  const u16* w3B  = W3  + wcol*2048 + (w>>1)*1024 + (w&1)*512 + ke*8;
  const int aRowH = (mg*16 + r16)*H_  + ke*8;
  const int aRowX = (mg*16 + r16)*FX_ + ke*8;
  const int hsel  = w >> 1;                     // 0: lower-layer half, 1: own-prev half
  const int hq    = (w & 1) * 512;
  const int mb = bid / 11, nt = bid - (bid/11)*11;  // decoder tile (bid<88)

  f32x4 gh[4], gl[4];
  zacc(gh, gl);                                 // carried L1-h partial; zero at t=0 (h0=0)

  for (int t = 0; t < T_; ++t){
    const int cur = t & 1, prv = cur ^ 1;

    // ---------- P1: L1 x-part (K=256) on carried h-part partial + cell ----------
    gemm<2, FX_>(w1xB, if_hi + aRowX + w*64, if_lo + aRowX + w*64, gh, gl);
    reduce_cell(gh, gl, bperm + 0*G_ + ug*64, cst + 0*BH_,
                h_hi + (0*2+cur)*BH_, h_lo + (0*2+cur)*BH_,
                mg, ug, w, ke, r16, tid, red);
    ++ep; gbar(bar, ep, tid, bid);

    // ---------- P2: L2 = [h0_cur | h1_prev], K=2048 ----------
    {
      const u16* ah = (hsel ? h_hi + (1*2+prv)*BH_ : h_hi + (0*2+cur)*BH_) + aRowH + hq;
      const u16* al = (hsel ? h_lo + (1*2+prv)*BH_ : h_lo + (0*2+cur)*BH_) + aRowH + hq;
      zacc(gh, gl);
      gemm<16, 2048>(w2B, ah, al, gh, gl);
      reduce_cell(gh, gl, bperm + 1*G_ + ug*64, cst + 1*BH_,
                  h_hi + (1*2+cur)*BH_, h_lo + (1*2+cur)*BH_,
                  mg, ug, w, ke, r16, tid, red);
    }
    ++ep; gbar(bar, ep, tid, bid);

    // ---------- P3: L3 = [h1_cur | h2_prev], K=2048 ----------
    {
      const u16* ah = (hsel ? h_hi + (2*2+prv)*BH_ : h_hi + (1*2+cur)*BH_) + aRowH + hq;
      const u16* al = (hsel ? h_lo + (2*2+prv)*BH_ : h_lo + (1*2+cur)*BH_) + aRowH + hq;
      zacc(gh, gl);
      gemm<16, 2048>(w3B, ah, al, gh, gl);
      reduce_cell(gh, gl, bperm + 2*G_ + ug*64, cst + 2*BH_,
                  h_hi + (2*2+cur)*BH_, h_lo + (2*2+cur)*BH_,
                  mg, ug, w, ke, r16, tid, red);
    }
    ++ep; gbar(bar, ep, tid, bid);

    // ---------- P4: decoder (88 blocks) + L1 h-part precompute for t+1 (all) ----------
    if (bid < 88){                               // 8 batch-tiles x 11 col-tiles
      const u16* ah = h_hi + (2*2+cur)*BH_ + (mb*16 + r16)*H_ + ke*8 + w*256;
      const u16* al = h_lo + (2*2+cur)*BH_ + (mb*16 + r16)*H_ + ke*8 + w*256;
      const u16* wd = WD + (size_t)(nt*16 + r16)*1024 + w*256 + ke*8;
      f32x4 d0 = {0,0,0,0}, d1 = {0,0,0,0};
#pragma unroll
      for (int kc = 0; kc < 8; ++kc){
        const bf16x8 bw = ld8(wd + kc*32);
        d0 = MFMA(ld8(ah + kc*32), bw, d0);
        d1 = MFMA(ld8(al + kc*32), bw, d1);
      }
#pragma unroll
      for (int r = 0; r < 4; ++r) red[w][ke*4 + r][r16] = d0[r] + d1[r];
      __syncthreads();
      {
        const int bl = tid >> 4, fl = tid & 15;
        const float v = red[0][bl][fl] + red[1][bl][fl]
                      + red[2][bl][fl] + red[3][bl][fl] + bdec[nt*16 + fl];
        const int f = nt*16 + fl, b = mb*16 + bl;
        if (f < F_) out[(size_t)b*TF_ + (size_t)t*F_ + f] = v;
        if (t + 1 < T_){
          float in = 0.f;
          if (f < F_){
            const bool gt = (((t+1) % 10) < 5);
            in = gt ? x[(size_t)b*TF_ + (size_t)(t+1)*F_ + f] : v;
          }
          const u16 hh = f2bf(in);
          if_hi[b*FX_ + f] = hh;
          if_lo[b*FX_ + f] = f2bf(in - bf2f(hh));
        }
      }
    }
    zacc(gh, gl);                                // L1 h-part on h0_cur (= h0_prev of t+1)
    gemm<8, 1024>(w1hB, h_hi + (0*2+cur)*BH_ + aRowH + w*256,
                         h_lo + (0*2+cur)*BH_ + aRowH + w*256, gh, gl);
    ++ep; gbar(bar, ep, tid, bid);               // gh/gl carry into P1 of t+1
  }
}

// ---------- prep: permuted biases, decoder bias, initial in_frame ----------
__global__ void k_prep(const float* __restrict__ x,
                       const float* bi1, const float* bh1,
                       const float* bi2, const float* bh2,
                       const float* bi3, const float* bh3,
                       const float* bd_in,
                       float* __restrict__ bperm, float* __restrict__ bdec,
                       u16* __restrict__ if_hi, u16* __restrict__ if_lo)
{
  const int i = blockIdx.x * blockDim.x + threadIdx.x;
  if (i < 3*G_){
    const int l = i >> 12, r = i & 4095;
    const int ug = r >> 6, g = (r >> 4) & 3, u = r & 15;
    const int j = (g << 10) | (ug << 4) | u;          // original gate row
    const float* bi = (l == 0) ? bi1 : (l == 1) ? bi2 : bi3;
    const float* bh = (l == 0) ? bh1 : (l == 1) ? bh2 : bh3;
    bperm[i] = bi[j] + bh[j];
  }
  const int i2 = i - 3*G_;
  if (i2 >= 0 && i2 < 192) bdec[i2] = (i2 < F_) ? bd_in[i2] : 0.f;
  const int i3 = i2 - 192;
  if (i3 >= 0 && i3 < B_*FX_){
    const int b = i3 >> 8, f = i3 & 255;
    const float v = (f < F_) ? x[(size_t)b*TF_ + f] : 0.f;   // t=0 is ground-truth
    const u16 hh = f2bf(v);
    if_hi[i3] = hh;
    if_lo[i3] = f2bf(v - bf2f(hh));
  }
}

// ---------- weight convert: fp32 -> bf16, gate-permuted ----------
__global__ void k_wcvt(const float* __restrict__ Wih1, const float* __restrict__ Whh1,
                       const float* __restrict__ Wih2, const float* __restrict__ Whh2,
                       const float* __restrict__ Wih3, const float* __restrict__ Whh3,
                       const float* __restrict__ Wd_in,
                       u16* __restrict__ W1X, u16* __restrict__ W1H,
                       u16* __restrict__ W2,  u16* __restrict__ W3,
                       u16* __restrict__ WD)
{
  const int region = blockIdx.y;
  const size_t stride = (size_t)gridDim.x * blockDim.x;
  const size_t i0 = (size_t)blockIdx.x * blockDim.x + threadIdx.x;
  if (region == 0){
    for (size_t i = i0; i < (size_t)G_*FX_; i += stride){
      const int r = (int)(i >> 8), k = (int)(i & 255);
      const int ug = r >> 6, g = (r >> 4) & 3, u = r & 15;
      const int j = (g << 10) | (ug << 4) | u;
      W1X[i] = f2bf((k < F_) ? Wih1[(size_t)j*F_ + k] : 0.f);
    }
  } else if (region == 1){
    for (size_t i = i0; i < (size_t)G_*H_; i += stride){
      const int r = (int)(i >> 10), k = (int)(i & 1023);
      const int ug = r >> 6, g = (r >> 4) & 3, u = r & 15;
      const int j = (g << 10) | (ug << 4) | u;
      W1H[i] = f2bf(Whh1[(size_t)j*H_ + k]);
    }
  } else if (region == 2){
    for (size_t i = i0; i < (size_t)G_*2048; i += stride){
      const int r = (int)(i >> 11), k = (int)(i & 2047);
      const int ug = r >> 6, g = (r >> 4) & 3, u = r & 15;
      const int j = (g << 10) | (ug << 4) | u;
      W2[i] = f2bf((k < H_) ? Wih2[(size_t)j*H_ + k] : Whh2[(size_t)j*H_ + (k - H_)]);
    }
  } else if (region == 3){
    for (size_t i = i0; i < (size_t)G_*2048; i += stride){
      const int r = (int)(i >> 11), k = (int)(i & 2047);
      const int ug = r >> 6, g = (r >> 4) & 3, u = r & 15;
      const int j = (g << 10) | (ug << 4) | u;
      W3[i] = f2bf((k < H_) ? Wih3[(size_t)j*H_ + k] : Whh3[(size_t)j*H_ + (k - H_)]);
    }
  } else {
    for (size_t i = i0; i < (size_t)176*H_; i += stride){
      const int r = (int)(i >> 10), k = (int)(i & 1023);
      WD[i] = f2bf((r < F_) ? Wd_in[(size_t)r*H_ + k] : 0.f);
    }
  }
}

extern "C" void kernel_launch(void* const* d_in, const int* in_sizes, int n_in,
                              void* d_out, int out_size, void* d_ws, size_t ws_size,
                              hipStream_t stream)
{
  const float* x    = (const float*)d_in[0];
  const float* Wih1 = (const float*)d_in[1];
  const float* bih1 = (const float*)d_in[2];
  const float* Whh1 = (const float*)d_in[3];
  const float* bhh1 = (const float*)d_in[4];
  const float* Wih2 = (const float*)d_in[5];
  const float* bih2 = (const float*)d_in[6];
  const float* Whh2 = (const float*)d_in[7];
  const float* bhh2 = (const float*)d_in[8];
  const float* Wih3 = (const float*)d_in[9];
  const float* bih3 = (const float*)d_in[10];
  const float* Whh3 = (const float*)d_in[11];
  const float* bhh3 = (const float*)d_in[12];
  const float* Wdec = (const float*)d_in[13];
  const float* bdec_in = (const float*)d_in[14];
  float* out = (float*)d_out;

  char* ws = (char*)d_ws;
  size_t off = 0;
  auto alloc = [&](size_t bytes) -> void* {
    void* p = ws + off;
    off = (off + bytes + 255) & ~(size_t)255;
    return p;
  };
  unsigned* bar = (unsigned*)alloc(4096);        // 32 leaves + root, 64B apart
  u16* h_hi  = (u16*)alloc((size_t)3*2*BH_*2);
  u16* h_lo  = (u16*)alloc((size_t)3*2*BH_*2);
  float* cst = (float*)alloc((size_t)3*BH_*4);
  u16* if_hi = (u16*)alloc((size_t)B_*FX_*2);
  u16* if_lo = (u16*)alloc((size_t)B_*FX_*2);
  const size_t zero_bytes = off;                 // state zone: re-zeroed every launch
  u16* W1X = (u16*)alloc((size_t)G_*FX_*2);
  u16* W1H = (u16*)alloc((size_t)G_*H_*2);
  u16* W2  = (u16*)alloc((size_t)G_*2048*2);
  u16* W3  = (u16*)alloc((size_t)G_*2048*2);
  u16* WD  = (u16*)alloc((size_t)176*H_*2);
  float* bperm = (float*)alloc((size_t)3*G_*4);
  float* bdec  = (float*)alloc((size_t)192*4);

  hipMemsetAsync(d_ws, 0, zero_bytes, stream);
  k_prep<<<180, 256, 0, stream>>>(x, bih1, bhh1, bih2, bhh2, bih3, bhh3, bdec_in,
                                  bperm, bdec, if_hi, if_lo);
  k_wcvt<<<dim3(2048, 5), 256, 0, stream>>>(Wih1, Whh1, Wih2, Whh2, Wih3, Whh3, Wdec,
                                            W1X, W1H, W2, W3, WD);
  k_main<<<NB_, NT_, 0, stream>>>(x, out, W1X, W1H, W2, W3, WD, bperm, bdec,
                                  h_hi, h_lo, cst, if_hi, if_lo, bar);
}

// Round 4
// 20379.079 us; speedup vs baseline: 3.5948x; 1.6266x over previous
//
#include <hip/hip_runtime.h>

typedef unsigned short u16;
typedef __attribute__((ext_vector_type(8))) short bf16x8;
typedef __attribute__((ext_vector_type(4))) float f32x4;

#define MFMA(a,b,c) __builtin_amdgcn_mfma_f32_16x16x32_bf16(a,b,c,0,0,0)

#define B_   128
#define T_   200
#define F_   171
#define FX_  256          // padded frame (8 K-chunks of 32; zero-padded weights)
#define H_   1024
#define G_   4096
#define TF_  (T_*F_)
#define BH_  (B_*H_)
#define NB_  512
#define NT_  256

__device__ __forceinline__ u16 f2bf(float v){
  union { float f; unsigned u; } c; c.f = v;
  unsigned r = (c.u + 0x7fffu + ((c.u >> 16) & 1u)) >> 16;   // RNE
  return (u16)r;
}
__device__ __forceinline__ float bf2f(u16 h){
  union { unsigned u; float f; } c; c.u = ((unsigned)h) << 16; return c.f;
}
__device__ __forceinline__ bf16x8 ld8(const u16* p){
  return *reinterpret_cast<const bf16x8*>(p);
}
__device__ __forceinline__ float sigm(float v){ return 1.f / (1.f + __expf(-v)); }

// ---------- group barrier (64 blocks = one 16-batch group) ----------
// FAST (group co-resident on one XCD): no fences. __syncthreads drains vmcnt,
// write-through L1 puts stores in the shared XCD L2; consumers' plain loads hit
// that L2; L1 staleness impossible by capacity (1.4 MB streamed between reuses).
// SLOW (mapping check failed): round-3 fence protocol (release-wb / acquire-inv).
__device__ __forceinline__ void group_bar(unsigned* gcnt, unsigned tgt, int tid, bool fast){
  __syncthreads();
  if (tid == 0){
    if (!fast) __builtin_amdgcn_fence(__ATOMIC_RELEASE, "agent");
    __hip_atomic_fetch_add(gcnt, 1u, __ATOMIC_RELAXED, __HIP_MEMORY_SCOPE_AGENT);
    while (__hip_atomic_load(gcnt, __ATOMIC_RELAXED, __HIP_MEMORY_SCOPE_AGENT) < tgt)
      __builtin_amdgcn_s_sleep(1);
    if (!fast) __builtin_amdgcn_fence(__ATOMIC_ACQUIRE, "agent");
  }
  asm volatile("" ::: "memory");
  __syncthreads();
}

// ---------- K-quarter GEMM: KC chunks of 32, 4 col-tiles, hi/lo into same acc ----------
template<int KC, int KS>
__device__ __forceinline__ void gemm(const u16* __restrict__ Wb,
                                     const u16* __restrict__ Ah, const u16* __restrict__ Al,
                                     f32x4 (&acc)[4])
{
#pragma unroll
  for (int kc = 0; kc < KC; ++kc){
    const bf16x8 pa = ld8(Ah + kc*32);
    const bf16x8 pl = ld8(Al + kc*32);
#pragma unroll
    for (int tt = 0; tt < 4; ++tt){
      const bf16x8 bw = ld8(Wb + (size_t)tt*16*KS + kc*32);
      acc[tt] = MFMA(pa, bw, acc[tt]);
      acc[tt] = MFMA(pl, bw, acc[tt]);
    }
  }
}
__device__ __forceinline__ void zacc(f32x4 (&acc)[4]){
#pragma unroll
  for (int i = 0; i < 4; ++i) acc[i] = (f32x4){0,0,0,0};
}

// ---------- cross-wave K-reduce + cell update (block: 16 batches x 16 units) ----------
__device__ __forceinline__ void reduce_cell(
    f32x4 (&acc)[4],
    const float* __restrict__ bias64, float* __restrict__ c_l,
    u16* __restrict__ ohh, u16* __restrict__ ohl,
    int g, int c, int w, int ke, int r16, int tid, float (*red)[16][69])
{
#pragma unroll
  for (int tt = 0; tt < 4; ++tt){
#pragma unroll
    for (int r = 0; r < 4; ++r)
      red[w][ke*4 + r][tt*16 + r16] = acc[tt][r];   // D: row=ke*4+r, col=lane&15
  }
  __syncthreads();
  {
    const int bl = tid >> 4, u = tid & 15;
    float gg[4];
#pragma unroll
    for (int q = 0; q < 4; ++q)
      gg[q] = red[0][bl][q*16+u] + red[1][bl][q*16+u]
            + red[2][bl][q*16+u] + red[3][bl][q*16+u] + bias64[q*16 + u];
    const int idx = (g*16 + bl)*H_ + c*16 + u;
    const float co = c_l[idx];
    const float cn = sigm(gg[1])*co + sigm(gg[0])*tanhf(gg[2]);
    const float hn = sigm(gg[3])*tanhf(cn);
    c_l[idx] = cn;
    const u16 hh = f2bf(hn);
    ohh[idx] = hh;
    ohl[idx] = f2bf(hn - bf2f(hh));
  }
}

// ---------- main persistent kernel: 512 blocks, group g=bid&7 (16 rows), c=bid>>3 ----------
__global__ __launch_bounds__(NT_, 2) void k_main(
    const float* __restrict__ x, float* __restrict__ out,
    const u16* __restrict__ W1X, const u16* __restrict__ W1H,
    const u16* __restrict__ W2,  const u16* __restrict__ W3,
    const u16* __restrict__ WD,
    const float* __restrict__ bperm, const float* __restrict__ bdec,
    u16* __restrict__ h_hi, u16* __restrict__ h_lo, float* __restrict__ cst,
    u16* __restrict__ if_hi, u16* __restrict__ if_lo,
    unsigned* __restrict__ bar)
{
  const int tid = threadIdx.x, bid = blockIdx.x;
  const int g = bid & 7, c = bid >> 3;          // group = batch rows g*16..+16; c = unit-group
  const int w = tid >> 6, lane = tid & 63;      // 4 waves split K
  const int r16 = lane & 15, ke = lane >> 4;
  __shared__ float red[4][16][69];
  unsigned ep = 0;

  // ---- one-time XCD co-residency check ----
  unsigned xcc; asm volatile("s_getreg_b32 %0, hwreg(HW_REG_XCC_ID)" : "=s"(xcc));
  xcc &= 7;
  unsigned* grpcnt = bar + g*64;                 // 256B-spaced per-group counters
  unsigned* root   = bar + 8*64;
  unsigned* chk    = bar + 9*64;                 // 8 groups x 16 xcc buckets
  if (tid == 0){
    __hip_atomic_fetch_add(&chk[g*16 + xcc], 1u, __ATOMIC_RELAXED, __HIP_MEMORY_SCOPE_AGENT);
    __builtin_amdgcn_fence(__ATOMIC_RELEASE, "agent");
    __hip_atomic_fetch_add(root, 1u, __ATOMIC_RELAXED, __HIP_MEMORY_SCOPE_AGENT);
    while (__hip_atomic_load(root, __ATOMIC_RELAXED, __HIP_MEMORY_SCOPE_AGENT) < (unsigned)NB_)
      __builtin_amdgcn_s_sleep(1);
    __builtin_amdgcn_fence(__ATOMIC_ACQUIRE, "agent");
  }
  __syncthreads();
  const bool fast =
    (__hip_atomic_load(&chk[g*16 + xcc], __ATOMIC_RELAXED, __HIP_MEMORY_SCOPE_AGENT) == 64u);

  const size_t wcol = (size_t)(c*64 + r16);
  const u16* w1xB = W1X + wcol*FX_  + w*64            + ke*8;   // K=256, quarter 64
  const u16* w1hB = W1H + wcol*1024 + w*256           + ke*8;   // K=1024, quarter 256
  const u16* w2B  = W2  + wcol*2048 + (w>>1)*1024 + (w&1)*512 + ke*8;
  const u16* w3B  = W3  + wcol*2048 + (w>>1)*1024 + (w&1)*512 + ke*8;
  const int aRowH = (g*16 + r16)*H_  + ke*8;
  const int aRowX = (g*16 + r16)*FX_ + ke*8;
  const int hsel  = w >> 1;                     // 0: lower-layer half, 1: own-prev half
  const int hq    = (w & 1) * 512;

  f32x4 acc[4];
  zacc(acc);                                    // carried L1-h partial; zero at t=0 (h0=0)

  for (int t = 0; t < T_; ++t){
    const int cur = t & 1, prv = cur ^ 1;

    // ---------- P1: L1 x-part (K=256) on carried h-part partial + cell ----------
    gemm<2, FX_>(w1xB, if_hi + aRowX + w*64, if_lo + aRowX + w*64, acc);
    reduce_cell(acc, bperm + 0*G_ + c*64, cst + 0*BH_,
                h_hi + (0*2+cur)*BH_, h_lo + (0*2+cur)*BH_,
                g, c, w, ke, r16, tid, red);
    ++ep; group_bar(grpcnt, ep*64u, tid, fast);

    // ---------- P2: L2 = [h0_cur | h1_prev], K=2048 ----------
    {
      const u16* ah = (hsel ? h_hi + (1*2+prv)*BH_ : h_hi + (0*2+cur)*BH_) + aRowH + hq;
      const u16* al = (hsel ? h_lo + (1*2+prv)*BH_ : h_lo + (0*2+cur)*BH_) + aRowH + hq;
      zacc(acc);
      gemm<16, 2048>(w2B, ah, al, acc);
      reduce_cell(acc, bperm + 1*G_ + c*64, cst + 1*BH_,
                  h_hi + (1*2+cur)*BH_, h_lo + (1*2+cur)*BH_,
                  g, c, w, ke, r16, tid, red);
    }
    ++ep; group_bar(grpcnt, ep*64u, tid, fast);

    // ---------- P3: L3 = [h1_cur | h2_prev], K=2048 ----------
    {
      const u16* ah = (hsel ? h_hi + (2*2+prv)*BH_ : h_hi + (1*2+cur)*BH_) + aRowH + hq;
      const u16* al = (hsel ? h_lo + (2*2+prv)*BH_ : h_lo + (1*2+cur)*BH_) + aRowH + hq;
      zacc(acc);
      gemm<16, 2048>(w3B, ah, al, acc);
      reduce_cell(acc, bperm + 2*G_ + c*64, cst + 2*BH_,
                  h_hi + (2*2+cur)*BH_, h_lo + (2*2+cur)*BH_,
                  g, c, w, ke, r16, tid, red);
    }
    ++ep; group_bar(grpcnt, ep*64u, tid, fast);

    // ---------- P4: decoder (group's c<11) + L1 h-part precompute for t+1 (all) ----------
    if (c < 11){                                  // 11 col-tiles cover F=171
      const u16* ah = h_hi + (2*2+cur)*BH_ + (g*16 + r16)*H_ + ke*8 + w*256;
      const u16* al = h_lo + (2*2+cur)*BH_ + (g*16 + r16)*H_ + ke*8 + w*256;
      const u16* wd = WD + (size_t)(c*16 + r16)*1024 + w*256 + ke*8;
      f32x4 d0 = {0,0,0,0}, d1 = {0,0,0,0};
#pragma unroll
      for (int kc = 0; kc < 8; ++kc){
        const bf16x8 bw = ld8(wd + kc*32);
        d0 = MFMA(ld8(ah + kc*32), bw, d0);
        d1 = MFMA(ld8(al + kc*32), bw, d1);
      }
#pragma unroll
      for (int r = 0; r < 4; ++r) red[w][ke*4 + r][r16] = d0[r] + d1[r];
      __syncthreads();
      {
        const int bl = tid >> 4, fl = tid & 15;
        const float v = red[0][bl][fl] + red[1][bl][fl]
                      + red[2][bl][fl] + red[3][bl][fl] + bdec[c*16 + fl];
        const int f = c*16 + fl, b = g*16 + bl;
        if (f < F_) out[(size_t)b*TF_ + (size_t)t*F_ + f] = v;
        if (t + 1 < T_){
          float in = 0.f;
          if (f < F_){
            const bool gt = (((t+1) % 10) < 5);
            in = gt ? x[(size_t)b*TF_ + (size_t)(t+1)*F_ + f] : v;
          }
          const u16 hh = f2bf(in);
          if_hi[b*FX_ + f] = hh;
          if_lo[b*FX_ + f] = f2bf(in - bf2f(hh));
        }
      }
    }
    zacc(acc);                                    // L1 h-part on h0_cur (= h0_prev of t+1)
    gemm<8, 1024>(w1hB, h_hi + (0*2+cur)*BH_ + aRowH + w*256,
                         h_lo + (0*2+cur)*BH_ + aRowH + w*256, acc);
    ++ep; group_bar(grpcnt, ep*64u, tid, fast);   // acc carries into P1 of t+1
  }
}

// ---------- prep: permuted biases, decoder bias, initial in_frame ----------
__global__ void k_prep(const float* __restrict__ x,
                       const float* bi1, const float* bh1,
                       const float* bi2, const float* bh2,
                       const float* bi3, const float* bh3,
                       const float* bd_in,
                       float* __restrict__ bperm, float* __restrict__ bdec,
                       u16* __restrict__ if_hi, u16* __restrict__ if_lo)
{
  const int i = blockIdx.x * blockDim.x + threadIdx.x;
  if (i < 3*G_){
    const int l = i >> 12, r = i & 4095;
    const int ug = r >> 6, g = (r >> 4) & 3, u = r & 15;
    const int j = (g << 10) | (ug << 4) | u;          // original gate row
    const float* bi = (l == 0) ? bi1 : (l == 1) ? bi2 : bi3;
    const float* bh = (l == 0) ? bh1 : (l == 1) ? bh2 : bh3;
    bperm[i] = bi[j] + bh[j];
  }
  const int i2 = i - 3*G_;
  if (i2 >= 0 && i2 < 192) bdec[i2] = (i2 < F_) ? bd_in[i2] : 0.f;
  const int i3 = i2 - 192;
  if (i3 >= 0 && i3 < B_*FX_){
    const int b = i3 >> 8, f = i3 & 255;
    const float v = (f < F_) ? x[(size_t)b*TF_ + f] : 0.f;   // t=0 is ground-truth
    const u16 hh = f2bf(v);
    if_hi[i3] = hh;
    if_lo[i3] = f2bf(v - bf2f(hh));
  }
}

// ---------- weight convert: fp32 -> bf16, gate-permuted ----------
__global__ void k_wcvt(const float* __restrict__ Wih1, const float* __restrict__ Whh1,
                       const float* __restrict__ Wih2, const float* __restrict__ Whh2,
                       const float* __restrict__ Wih3, const float* __restrict__ Whh3,
                       const float* __restrict__ Wd_in,
                       u16* __restrict__ W1X, u16* __restrict__ W1H,
                       u16* __restrict__ W2,  u16* __restrict__ W3,
                       u16* __restrict__ WD)
{
  const int region = blockIdx.y;
  const size_t stride = (size_t)gridDim.x * blockDim.x;
  const size_t i0 = (size_t)blockIdx.x * blockDim.x + threadIdx.x;
  if (region == 0){
    for (size_t i = i0; i < (size_t)G_*FX_; i += stride){
      const int r = (int)(i >> 8), k = (int)(i & 255);
      const int ug = r >> 6, g = (r >> 4) & 3, u = r & 15;
      const int j = (g << 10) | (ug << 4) | u;
      W1X[i] = f2bf((k < F_) ? Wih1[(size_t)j*F_ + k] : 0.f);
    }
  } else if (region == 1){
    for (size_t i = i0; i < (size_t)G_*H_; i += stride){
      const int r = (int)(i >> 10), k = (int)(i & 1023);
      const int ug = r >> 6, g = (r >> 4) & 3, u = r & 15;
      const int j = (g << 10) | (ug << 4) | u;
      W1H[i] = f2bf(Whh1[(size_t)j*H_ + k]);
    }
  } else if (region == 2){
    for (size_t i = i0; i < (size_t)G_*2048; i += stride){
      const int r = (int)(i >> 11), k = (int)(i & 2047);
      const int ug = r >> 6, g = (r >> 4) & 3, u = r & 15;
      const int j = (g << 10) | (ug << 4) | u;
      W2[i] = f2bf((k < H_) ? Wih2[(size_t)j*H_ + k] : Whh2[(size_t)j*H_ + (k - H_)]);
    }
  } else if (region == 3){
    for (size_t i = i0; i < (size_t)G_*2048; i += stride){
      const int r = (int)(i >> 11), k = (int)(i & 2047);
      const int ug = r >> 6, g = (r >> 4) & 3, u = r & 15;
      const int j = (g << 10) | (ug << 4) | u;
      W3[i] = f2bf((k < H_) ? Wih3[(size_t)j*H_ + k] : Whh3[(size_t)j*H_ + (k - H_)]);
    }
  } else {
    for (size_t i = i0; i < (size_t)176*H_; i += stride){
      const int r = (int)(i >> 10), k = (int)(i & 1023);
      WD[i] = f2bf((r < F_) ? Wd_in[(size_t)r*H_ + k] : 0.f);
    }
  }
}

extern "C" void kernel_launch(void* const* d_in, const int* in_sizes, int n_in,
                              void* d_out, int out_size, void* d_ws, size_t ws_size,
                              hipStream_t stream)
{
  const float* x    = (const float*)d_in[0];
  const float* Wih1 = (const float*)d_in[1];
  const float* bih1 = (const float*)d_in[2];
  const float* Whh1 = (const float*)d_in[3];
  const float* bhh1 = (const float*)d_in[4];
  const float* Wih2 = (const float*)d_in[5];
  const float* bih2 = (const float*)d_in[6];
  const float* Whh2 = (const float*)d_in[7];
  const float* bhh2 = (const float*)d_in[8];
  const float* Wih3 = (const float*)d_in[9];
  const float* bih3 = (const float*)d_in[10];
  const float* Whh3 = (const float*)d_in[11];
  const float* bhh3 = (const float*)d_in[12];
  const float* Wdec = (const float*)d_in[13];
  const float* bdec_in = (const float*)d_in[14];
  float* out = (float*)d_out;

  char* ws = (char*)d_ws;
  size_t off = 0;
  auto alloc = [&](size_t bytes) -> void* {
    void* p = ws + off;
    off = (off + bytes + 255) & ~(size_t)255;
    return p;
  };
  unsigned* bar = (unsigned*)alloc(8192);        // group counters + root + chk buckets
  u16* h_hi  = (u16*)alloc((size_t)3*2*BH_*2);
  u16* h_lo  = (u16*)alloc((size_t)3*2*BH_*2);
  float* cst = (float*)alloc((size_t)3*BH_*4);
  u16* if_hi = (u16*)alloc((size_t)B_*FX_*2);
  u16* if_lo = (u16*)alloc((size_t)B_*FX_*2);
  const size_t zero_bytes = off;                 // state zone: re-zeroed every launch
  u16* W1X = (u16*)alloc((size_t)G_*FX_*2);
  u16* W1H = (u16*)alloc((size_t)G_*H_*2);
  u16* W2  = (u16*)alloc((size_t)G_*2048*2);
  u16* W3  = (u16*)alloc((size_t)G_*2048*2);
  u16* WD  = (u16*)alloc((size_t)176*H_*2);
  float* bperm = (float*)alloc((size_t)3*G_*4);
  float* bdec  = (float*)alloc((size_t)192*4);

  hipMemsetAsync(d_ws, 0, zero_bytes, stream);
  k_prep<<<180, 256, 0, stream>>>(x, bih1, bhh1, bih2, bhh2, bih3, bhh3, bdec_in,
                                  bperm, bdec, if_hi, if_lo);
  k_wcvt<<<dim3(2048, 5), 256, 0, stream>>>(Wih1, Whh1, Wih2, Whh2, Wih3, Whh3, Wdec,
                                            W1X, W1H, W2, W3, WD);
  k_main<<<NB_, NT_, 0, stream>>>(x, out, W1X, W1H, W2, W3, WD, bperm, bdec,
                                  h_hi, h_lo, cst, if_hi, if_lo, bar);
}